// Round 1
// baseline (18248.961 us; speedup 1.0000x reference)
//
#include <hip/hip_runtime.h>
#include <math.h>

#define BB 8
#define TT 256
#define HH 768
#define NL 12
#define NH_ 12
#define DH_ 64
#define FF_ 3072
#define LH_ 256
#define KK_ 9

static __device__ __forceinline__ float sigmf(float x) { return 1.0f / (1.0f + expf(-x)); }

// ---------------- block reduce ----------------
__device__ float block_reduce_sum(float v, float* red) {
    int tid = threadIdx.x;
    red[tid] = v; __syncthreads();
    for (int s = 128; s > 0; s >>= 1) {
        if (tid < s) red[tid] += red[tid + s];
        __syncthreads();
    }
    float r = red[0]; __syncthreads();
    return r;
}

// ---------------- embedding + LN ----------------
__global__ __launch_bounds__(256) void embed_ln_kernel(
    const int* __restrict__ ids, const float* __restrict__ we, const float* __restrict__ pe,
    const float* __restrict__ te, const float* __restrict__ g, const float* __restrict__ b,
    float* __restrict__ out) {
    int row = blockIdx.x;        // b*T + t
    int t = row % TT;
    int id = ids[row];
    __shared__ float xr[HH];
    __shared__ float red[256];
    int tid = threadIdx.x;
    float s = 0.f;
    for (int h = tid; h < HH; h += 256) {
        float v = we[(size_t)id * HH + h] + pe[(size_t)t * HH + h] + te[h];
        xr[h] = v; s += v;
    }
    float mean = block_reduce_sum(s, red) * (1.0f / HH);
    float vs = 0.f;
    for (int h = tid; h < HH; h += 256) { float d = xr[h] - mean; vs += d * d; }
    float var = block_reduce_sum(vs, red) * (1.0f / HH);
    float rstd = rsqrtf(var + 1e-12f);
    for (int h = tid; h < HH; h += 256)
        out[(size_t)row * HH + h] = (xr[h] - mean) * rstd * g[h] + b[h];
}

// ---------------- LN(a + f) ----------------
__global__ __launch_bounds__(256) void ln_residual_kernel(
    const float* __restrict__ a, const float* __restrict__ f,
    const float* __restrict__ g, const float* __restrict__ b, float* __restrict__ out) {
    int row = blockIdx.x;
    __shared__ float xr[HH];
    __shared__ float red[256];
    int tid = threadIdx.x;
    float s = 0.f;
    for (int h = tid; h < HH; h += 256) {
        float v = a[(size_t)row * HH + h] + f[(size_t)row * HH + h];
        xr[h] = v; s += v;
    }
    float mean = block_reduce_sum(s, red) * (1.0f / HH);
    float vs = 0.f;
    for (int h = tid; h < HH; h += 256) { float d = xr[h] - mean; vs += d * d; }
    float var = block_reduce_sum(vs, red) * (1.0f / HH);
    float rstd = rsqrtf(var + 1e-12f);
    for (int h = tid; h < HH; h += 256)
        out[(size_t)row * HH + h] = (xr[h] - mean) * rstd * g[h] + b[h];
}

// ---------------- generic fp32 GEMM: C = A(MxK) * B + bias, opt Btrans/GELU ----------------
template <bool TRANSB, bool GELU>
__global__ __launch_bounds__(256) void gemm_kernel(
    const float* __restrict__ A, const float* __restrict__ B, const float* __restrict__ bias,
    float* __restrict__ C, int M, int N, int K) {
    __shared__ float As[16][68];
    __shared__ float Bs[16][68];
    int tid = threadIdx.x;
    int m0 = blockIdx.y * 64, n0 = blockIdx.x * 64;
    int tm = tid & 15, tn = tid >> 4;
    float acc[4][4] = {};
    for (int k0 = 0; k0 < K; k0 += 16) {
        {   // A tile: As[k][m] = A[(m0+m)*K + k0+k]
            int lk = tid & 15, mb = tid >> 4;
#pragma unroll
            for (int r = 0; r < 4; ++r) {
                int m = mb + 16 * r;
                As[lk][m] = A[(size_t)(m0 + m) * K + k0 + lk];
            }
        }
        if (!TRANSB) {   // B is K x N
            int n = tid & 63, k4 = tid >> 6;
#pragma unroll
            for (int kk = 0; kk < 4; ++kk) {
                int k = k4 * 4 + kk;
                Bs[k][n] = B[(size_t)(k0 + k) * N + n0 + n];
            }
        } else {         // B is N x K
            int lk = tid & 15, nb = tid >> 4;
#pragma unroll
            for (int r = 0; r < 4; ++r) {
                int n = nb + 16 * r;
                Bs[lk][n] = B[(size_t)(n0 + n) * K + k0 + lk];
            }
        }
        __syncthreads();
#pragma unroll
        for (int k = 0; k < 16; ++k) {
            float4 a4 = *(const float4*)&As[k][tm * 4];
            float4 b4 = *(const float4*)&Bs[k][tn * 4];
            float av[4] = {a4.x, a4.y, a4.z, a4.w};
            float bv[4] = {b4.x, b4.y, b4.z, b4.w};
#pragma unroll
            for (int i = 0; i < 4; ++i)
#pragma unroll
                for (int j = 0; j < 4; ++j) acc[i][j] += av[i] * bv[j];
        }
        __syncthreads();
    }
#pragma unroll
    for (int i = 0; i < 4; ++i) {
        int row = m0 + tm * 4 + i;
#pragma unroll
        for (int j = 0; j < 4; ++j) {
            int col = n0 + tn * 4 + j;
            float v = acc[i][j] + bias[col];
            if (GELU) v = 0.5f * v * (1.0f + erff(v * 0.70710678118654752f));
            C[(size_t)row * N + col] = v;
        }
    }
}

// ---------------- attention: per (b,head) block, thread = query row ----------------
__global__ __launch_bounds__(256) void attention_kernel(
    const float* __restrict__ q, const float* __restrict__ k, const float* __restrict__ v,
    const int* __restrict__ mask, float* __restrict__ ctx) {
    int bh = blockIdx.x;
    int b = bh / NH_, h = bh % NH_;
    int t = threadIdx.x;
    const float scale = 0.125f;
    float4 qv[16];
    const float4* qp = (const float4*)(q + ((size_t)(b * TT + t) * HH + h * DH_));
#pragma unroll
    for (int d = 0; d < 16; ++d) qv[d] = qp[d];
    const float* kbase = k + ((size_t)b * TT * HH + h * DH_);
    const float* vbase = v + ((size_t)b * TT * HH + h * DH_);
    __shared__ float bias_s[TT];
    bias_s[t] = (1.0f - (float)mask[b * TT + t]) * -10000.0f;
    __syncthreads();
    float mx = -1e30f;
    for (int kk = 0; kk < TT; ++kk) {
        const float4* kp = (const float4*)(kbase + (size_t)kk * HH);
        float s = 0.f;
#pragma unroll
        for (int d = 0; d < 16; ++d) {
            float4 k4 = kp[d];
            s += qv[d].x * k4.x + qv[d].y * k4.y + qv[d].z * k4.z + qv[d].w * k4.w;
        }
        s = s * scale + bias_s[kk];
        mx = fmaxf(mx, s);
    }
    float acc[64] = {};
    float l = 0.f;
    for (int kk = 0; kk < TT; ++kk) {
        const float4* kp = (const float4*)(kbase + (size_t)kk * HH);
        float s = 0.f;
#pragma unroll
        for (int d = 0; d < 16; ++d) {
            float4 k4 = kp[d];
            s += qv[d].x * k4.x + qv[d].y * k4.y + qv[d].z * k4.z + qv[d].w * k4.w;
        }
        s = s * scale + bias_s[kk];
        float p = expf(s - mx);
        l += p;
        const float4* vp = (const float4*)(vbase + (size_t)kk * HH);
#pragma unroll
        for (int d = 0; d < 16; ++d) {
            float4 v4 = vp[d];
            acc[4 * d + 0] += p * v4.x;
            acc[4 * d + 1] += p * v4.y;
            acc[4 * d + 2] += p * v4.z;
            acc[4 * d + 3] += p * v4.w;
        }
    }
    float inv = 1.0f / l;
    float4* cp = (float4*)(ctx + ((size_t)(b * TT + t) * HH + h * DH_));
#pragma unroll
    for (int d = 0; d < 16; ++d) {
        float4 o;
        o.x = acc[4 * d + 0] * inv;
        o.y = acc[4 * d + 1] * inv;
        o.z = acc[4 * d + 2] * inv;
        o.w = acc[4 * d + 3] * inv;
        cp[d] = o;
    }
}

// ---------------- LSTM scan: block = (dir, batch), 1024 threads = gates ----------------
__global__ __launch_bounds__(1024) void lstm_kernel(
    const float* __restrict__ xg_f, const float* __restrict__ xg_b,
    const float* __restrict__ whh_f, const float* __restrict__ whh_b,
    const float* __restrict__ bhh_f, const float* __restrict__ bhh_b,
    float* __restrict__ hf, float* __restrict__ hb) {
    int dir = blockIdx.x >> 3;
    int b = blockIdx.x & 7;
    const float* xg = dir ? xg_b : xg_f;
    const float* whh = dir ? whh_b : whh_f;
    const float* bhh = dir ? bhh_b : bhh_f;
    float* hout = dir ? hb : hf;
    int g = threadIdx.x;  // 0..1023
    __shared__ float h_s[LH_], c_s[LH_];
    __shared__ float g_s[4 * LH_];
    if (g < LH_) { h_s[g] = 0.f; c_s[g] = 0.f; }
    float bbias = bhh[g];
    const float4* wrow = (const float4*)(whh + (size_t)g * LH_);
    __syncthreads();
    for (int step = 0; step < TT; ++step) {
        int t = dir ? (TT - 1 - step) : step;
        float acc = xg[((size_t)b * TT + t) * (4 * LH_) + g] + bbias;
#pragma unroll 8
        for (int kk = 0; kk < LH_ / 4; ++kk) {
            float4 w4 = wrow[kk];
            float4 h4 = ((const float4*)h_s)[kk];
            acc += w4.x * h4.x + w4.y * h4.y + w4.z * h4.z + w4.w * h4.w;
        }
        g_s[g] = acc;
        __syncthreads();
        if (g < LH_) {
            float ig = sigmf(g_s[g]);
            float fg = sigmf(g_s[LH_ + g]);
            float gg = tanhf(g_s[2 * LH_ + g]);
            float og = sigmf(g_s[3 * LH_ + g]);
            float c = fg * c_s[g] + ig * gg;
            float hh = og * tanhf(c);
            c_s[g] = c; h_s[g] = hh;
            hout[((size_t)b * TT + t) * LH_ + g] = hh;
        }
        __syncthreads();
    }
}

// ---------------- classifier: em = [hf;hb] @ W_clf + b ----------------
__global__ __launch_bounds__(256) void clf_kernel(
    const float* __restrict__ hf, const float* __restrict__ hb,
    const float* __restrict__ W, const float* __restrict__ bias, float* __restrict__ em) {
    int idx = blockIdx.x * blockDim.x + threadIdx.x;
    if (idx >= BB * TT * KK_) return;
    int row = idx / KK_, j = idx % KK_;
    float acc = bias[j];
    const float* hfp = hf + (size_t)row * LH_;
    const float* hbp = hb + (size_t)row * LH_;
    for (int kk = 0; kk < LH_; ++kk) acc += hfp[kk] * W[kk * KK_ + j];
    for (int kk = 0; kk < LH_; ++kk) acc += hbp[kk] * W[(LH_ + kk) * KK_ + j];
    em[idx] = acc;
}

// ---------------- CRF: single block ----------------
__global__ __launch_bounds__(128) void crf_kernel(
    const float* __restrict__ em, const int* __restrict__ labels, const int* __restrict__ mask,
    const float* __restrict__ cstart, const float* __restrict__ cend,
    const float* __restrict__ ctrans, float* __restrict__ out) {
    __shared__ float alpha[BB][KK_], nxt[BB][KK_], trans[KK_ * KK_];
    __shared__ float score_s[BB], logZ_s[BB];
    int tid = threadIdx.x;
    if (tid < KK_ * KK_) trans[tid] = ctrans[tid];
    __syncthreads();
    int b = tid / KK_, j = tid % KK_;
    if (tid < BB * KK_) alpha[b][j] = cstart[j] + em[(size_t)b * TT * KK_ + j];
    __syncthreads();
    for (int t = 1; t < TT; ++t) {
        if (tid < BB * KK_) {
            float m = -1e30f;
            for (int i = 0; i < KK_; ++i) m = fmaxf(m, alpha[b][i] + trans[i * KK_ + j]);
            float s = 0.f;
            for (int i = 0; i < KK_; ++i) s += expf(alpha[b][i] + trans[i * KK_ + j] - m);
            float nv = m + logf(s) + em[((size_t)b * TT + t) * KK_ + j];
            nxt[b][j] = (mask[b * TT + t] > 0) ? nv : alpha[b][j];
        }
        __syncthreads();
        if (tid < BB * KK_) alpha[b][j] = nxt[b][j];
        __syncthreads();
    }
    if (tid < BB) {
        int bb = tid;
        int l0 = labels[bb * TT];
        float sc = cstart[l0] + em[(size_t)bb * TT * KK_ + l0];
        int prev = l0;
        for (int t = 1; t < TT; ++t) {
            int lt = labels[bb * TT + t];
            float mf = (float)mask[bb * TT + t];
            sc += (trans[prev * KK_ + lt] + em[((size_t)bb * TT + t) * KK_ + lt]) * mf;
            prev = lt;
        }
        int ends = 0;
        for (int t = 0; t < TT; ++t) ends += mask[bb * TT + t];
        ends -= 1;
        int last = labels[bb * TT + ends];
        sc += cend[last];
        score_s[bb] = sc;
        float m = -1e30f;
        for (int jj = 0; jj < KK_; ++jj) m = fmaxf(m, alpha[bb][jj] + cend[jj]);
        float s = 0.f;
        for (int jj = 0; jj < KK_; ++jj) s += expf(alpha[bb][jj] + cend[jj] - m);
        logZ_s[bb] = m + logf(s);
    }
    __syncthreads();
    if (tid == 0) {
        float acc = 0.f;
        for (int bb = 0; bb < BB; ++bb) acc += score_s[bb] - logZ_s[bb];
        out[0] = -acc / (float)BB;
    }
}

extern "C" void kernel_launch(void* const* d_in, const int* in_sizes, int n_in,
                              void* d_out, int out_size, void* d_ws, size_t ws_size,
                              hipStream_t stream) {
    const int* input_ids = (const int*)d_in[0];
    const int* attn_mask = (const int*)d_in[1];
    const int* labels    = (const int*)d_in[2];
    const float* word_emb = (const float*)d_in[3];
    const float* pos_emb  = (const float*)d_in[4];
    const float* type_emb = (const float*)d_in[5];
    const float* emb_ln_g = (const float*)d_in[6];
    const float* emb_ln_b = (const float*)d_in[7];
    const float* Wq = (const float*)d_in[8];
    const float* bq = (const float*)d_in[9];
    const float* Wk = (const float*)d_in[10];
    const float* bk = (const float*)d_in[11];
    const float* Wv = (const float*)d_in[12];
    const float* bv = (const float*)d_in[13];
    const float* Wo = (const float*)d_in[14];
    const float* bo = (const float*)d_in[15];
    const float* ln1_g = (const float*)d_in[16];
    const float* ln1_b = (const float*)d_in[17];
    const float* Wf1 = (const float*)d_in[18];
    const float* bf1 = (const float*)d_in[19];
    const float* Wf2 = (const float*)d_in[20];
    const float* bf2 = (const float*)d_in[21];
    const float* ln2_g = (const float*)d_in[22];
    const float* ln2_b = (const float*)d_in[23];
    const float* w_ih_f = (const float*)d_in[24];
    const float* w_hh_f = (const float*)d_in[25];
    const float* b_ih_f = (const float*)d_in[26];
    const float* b_hh_f = (const float*)d_in[27];
    const float* w_ih_b = (const float*)d_in[28];
    const float* w_hh_b = (const float*)d_in[29];
    const float* b_ih_b = (const float*)d_in[30];
    const float* b_hh_b = (const float*)d_in[31];
    const float* W_clf  = (const float*)d_in[32];
    const float* b_clf  = (const float*)d_in[33];
    const float* crf_start = (const float*)d_in[34];
    const float* crf_end   = (const float*)d_in[35];
    const float* crf_trans = (const float*)d_in[36];

    const size_t NTOK = (size_t)BB * TT;          // 2048
    const size_t SZ = NTOK * HH;                  // 1,572,864 floats
    float* ws = (float*)d_ws;
    float* x    = ws;
    float* qb   = x + SZ;
    float* kb   = qb + SZ;
    float* vb   = kb + SZ;
    float* ctx  = vb + SZ;
    float* ab   = ctx + SZ;
    float* tmp  = ab + SZ;
    float* big  = tmp + SZ;                       // 2048*3072 floats

    embed_ln_kernel<<<NTOK, 256, 0, stream>>>(input_ids, word_emb, pos_emb, type_emb,
                                              emb_ln_g, emb_ln_b, x);

    dim3 gH(HH / 64, NTOK / 64);     // 12 x 32
    dim3 gF(FF_ / 64, NTOK / 64);    // 48 x 32
    dim3 gG(4 * LH_ / 64, NTOK / 64);// 16 x 32

    for (int l = 0; l < NL; ++l) {
        const float* wq = Wq + (size_t)l * HH * HH;
        const float* wk = Wk + (size_t)l * HH * HH;
        const float* wv = Wv + (size_t)l * HH * HH;
        const float* wo = Wo + (size_t)l * HH * HH;
        const float* bq_l = bq + (size_t)l * HH;
        const float* bk_l = bk + (size_t)l * HH;
        const float* bv_l = bv + (size_t)l * HH;
        const float* bo_l = bo + (size_t)l * HH;
        const float* g1 = ln1_g + (size_t)l * HH;
        const float* b1 = ln1_b + (size_t)l * HH;
        const float* wf1 = Wf1 + (size_t)l * HH * FF_;
        const float* bf1_l = bf1 + (size_t)l * FF_;
        const float* wf2 = Wf2 + (size_t)l * FF_ * HH;
        const float* bf2_l = bf2 + (size_t)l * HH;
        const float* g2 = ln2_g + (size_t)l * HH;
        const float* b2 = ln2_b + (size_t)l * HH;

        gemm_kernel<false, false><<<gH, 256, 0, stream>>>(x, wq, bq_l, qb, NTOK, HH, HH);
        gemm_kernel<false, false><<<gH, 256, 0, stream>>>(x, wk, bk_l, kb, NTOK, HH, HH);
        gemm_kernel<false, false><<<gH, 256, 0, stream>>>(x, wv, bv_l, vb, NTOK, HH, HH);
        attention_kernel<<<BB * NH_, 256, 0, stream>>>(qb, kb, vb, attn_mask, ctx);
        gemm_kernel<false, false><<<gH, 256, 0, stream>>>(ctx, wo, bo_l, tmp, NTOK, HH, HH);
        ln_residual_kernel<<<NTOK, 256, 0, stream>>>(x, tmp, g1, b1, ab);
        gemm_kernel<false, true><<<gF, 256, 0, stream>>>(ab, wf1, bf1_l, big, NTOK, FF_, HH);
        gemm_kernel<false, false><<<gH, 256, 0, stream>>>(big, wf2, bf2_l, tmp, NTOK, HH, FF_);
        ln_residual_kernel<<<NTOK, 256, 0, stream>>>(ab, tmp, g2, b2, x);
    }

    // LSTM input projections: xg[b,t,g] = x[b,t,:] . w_ih[g,:] + b_ih[g]
    float* xg_f = big;
    float* xg_b = big + NTOK * (size_t)(4 * LH_);
    gemm_kernel<true, false><<<gG, 256, 0, stream>>>(x, w_ih_f, b_ih_f, xg_f, NTOK, 4 * LH_, HH);
    gemm_kernel<true, false><<<gG, 256, 0, stream>>>(x, w_ih_b, b_ih_b, xg_b, NTOK, 4 * LH_, HH);

    float* hf = qb;
    float* hb = kb;
    float* em = vb;
    lstm_kernel<<<16, 1024, 0, stream>>>(xg_f, xg_b, w_hh_f, w_hh_b, b_hh_f, b_hh_b, hf, hb);
    clf_kernel<<<(BB * TT * KK_ + 255) / 256, 256, 0, stream>>>(hf, hb, W_clf, b_clf, em);
    crf_kernel<<<1, 128, 0, stream>>>(em, labels, attn_mask, crf_start, crf_end, crf_trans,
                                      (float*)d_out);
}

// Round 2
// 9807.420 us; speedup vs baseline: 1.8607x; 1.8607x over previous
//
#include <hip/hip_runtime.h>
#include <math.h>

#define BB 8
#define TT 256
#define HH 768
#define NL 12
#define NH_ 12
#define DH_ 64
#define FF_ 3072
#define LH_ 256
#define KK_ 9

typedef unsigned short u16;
typedef unsigned int u32;
typedef __attribute__((ext_vector_type(8))) short bf16x8;
typedef __attribute__((ext_vector_type(4))) float f32x4;

static __device__ __forceinline__ float sigmf(float x) { return 1.0f / (1.0f + expf(-x)); }

static __device__ __forceinline__ u16 f2bf(float f) {
    u32 u = __float_as_uint(f);
    u += 0x7fffu + ((u >> 16) & 1u);
    return (u16)(u >> 16);
}

// ---------------- block reduce ----------------
__device__ float block_reduce_sum(float v, float* red) {
    int tid = threadIdx.x;
    red[tid] = v; __syncthreads();
    for (int s = 128; s > 0; s >>= 1) {
        if (tid < s) red[tid] += red[tid + s];
        __syncthreads();
    }
    float r = red[0]; __syncthreads();
    return r;
}

// ---------------- embedding + LN ----------------
__global__ __launch_bounds__(256) void embed_ln_kernel(
    const int* __restrict__ ids, const float* __restrict__ we, const float* __restrict__ pe,
    const float* __restrict__ te, const float* __restrict__ g, const float* __restrict__ b,
    float* __restrict__ out) {
    int row = blockIdx.x;        // b*T + t
    int t = row % TT;
    int id = ids[row];
    __shared__ float xr[HH];
    __shared__ float red[256];
    int tid = threadIdx.x;
    float s = 0.f;
    for (int h = tid; h < HH; h += 256) {
        float v = we[(size_t)id * HH + h] + pe[(size_t)t * HH + h] + te[h];
        xr[h] = v; s += v;
    }
    float mean = block_reduce_sum(s, red) * (1.0f / HH);
    float vs = 0.f;
    for (int h = tid; h < HH; h += 256) { float d = xr[h] - mean; vs += d * d; }
    float var = block_reduce_sum(vs, red) * (1.0f / HH);
    float rstd = rsqrtf(var + 1e-12f);
    for (int h = tid; h < HH; h += 256)
        out[(size_t)row * HH + h] = (xr[h] - mean) * rstd * g[h] + b[h];
}

// ---------------- LN(a + f) ----------------
__global__ __launch_bounds__(256) void ln_residual_kernel(
    const float* __restrict__ a, const float* __restrict__ f,
    const float* __restrict__ g, const float* __restrict__ b, float* __restrict__ out) {
    int row = blockIdx.x;
    __shared__ float xr[HH];
    __shared__ float red[256];
    int tid = threadIdx.x;
    float s = 0.f;
    for (int h = tid; h < HH; h += 256) {
        float v = a[(size_t)row * HH + h] + f[(size_t)row * HH + h];
        xr[h] = v; s += v;
    }
    float mean = block_reduce_sum(s, red) * (1.0f / HH);
    float vs = 0.f;
    for (int h = tid; h < HH; h += 256) { float d = xr[h] - mean; vs += d * d; }
    float var = block_reduce_sum(vs, red) * (1.0f / HH);
    float rstd = rsqrtf(var + 1e-12f);
    for (int h = tid; h < HH; h += 256)
        out[(size_t)row * HH + h] = (xr[h] - mean) * rstd * g[h] + b[h];
}

// ---------------- bf16 MFMA GEMM ----------------
// C(MxN) = A(MxK) * B + bias, optional exact GELU.
// A: fp32 row-major [M][K]. B: fp32; if B_IS_NK, B is [N][K] (i.e. B^T storage,
// used for x @ w_ih^T); else B is [K][N] (transposed into LDS during staging).
// Staging converts fp32 -> bf16 (RNE). MFMA: 16x16x32 bf16, 4 waves in 2x2,
// each wave a 32x32 quadrant (2x2 fragments). LDS tiles padded [64][40] bf16.
template <bool B_IS_NK, bool GELU>
__global__ __launch_bounds__(256) void gemm_mfma_kernel(
    const float* __restrict__ A, const float* __restrict__ B, const float* __restrict__ bias,
    float* __restrict__ C, int M, int N, int K) {
    __shared__ u16 Als[64][40];
    __shared__ u16 Bls[64][40];
    int tid = threadIdx.x;
    int m0 = blockIdx.y * 64, n0 = blockIdx.x * 64;
    int lane = tid & 63;
    int w = tid >> 6;
    int wr = w >> 1, wc = w & 1;

    f32x4 zero = {0.f, 0.f, 0.f, 0.f};
    f32x4 acc00 = zero, acc01 = zero, acc10 = zero, acc11 = zero;

    int l15 = lane & 15;
    int kg8 = (lane >> 4) * 8;

    for (int k0 = 0; k0 < K; k0 += 32) {
        // ---- stage A: rows m0..m0+63, cols k0..k0+31, fp32 -> bf16 ----
        {
            int r = tid >> 2, q = tid & 3;
            const float* ap = &A[(size_t)(m0 + r) * K + k0 + q * 8];
            float4 a0 = *(const float4*)ap;
            float4 a1 = *(const float4*)(ap + 4);
            bf16x8 av;
            av[0] = (short)f2bf(a0.x); av[1] = (short)f2bf(a0.y);
            av[2] = (short)f2bf(a0.z); av[3] = (short)f2bf(a0.w);
            av[4] = (short)f2bf(a1.x); av[5] = (short)f2bf(a1.y);
            av[6] = (short)f2bf(a1.z); av[7] = (short)f2bf(a1.w);
            *(bf16x8*)&Als[r][q * 8] = av;
        }
        // ---- stage B into Bls[n][k] ----
        if (B_IS_NK) {
            int r = tid >> 2, q = tid & 3;
            const float* bp = &B[(size_t)(n0 + r) * K + k0 + q * 8];
            float4 b0 = *(const float4*)bp;
            float4 b1 = *(const float4*)(bp + 4);
            bf16x8 bv;
            bv[0] = (short)f2bf(b0.x); bv[1] = (short)f2bf(b0.y);
            bv[2] = (short)f2bf(b0.z); bv[3] = (short)f2bf(b0.w);
            bv[4] = (short)f2bf(b1.x); bv[5] = (short)f2bf(b1.y);
            bv[6] = (short)f2bf(b1.z); bv[7] = (short)f2bf(b1.w);
            *(bf16x8*)&Bls[r][q * 8] = bv;
        } else {
            int pr = tid >> 4;        // k-pair 0..15 -> k = 2*pr
            int nq = tid & 15;        // n-group -> n = 4*nq
            const float* b0p = &B[(size_t)(k0 + 2 * pr) * N + n0 + 4 * nq];
            const float* b1p = b0p + N;
            float4 x0 = *(const float4*)b0p;
            float4 x1 = *(const float4*)b1p;
            float v0[4] = {x0.x, x0.y, x0.z, x0.w};
            float v1[4] = {x1.x, x1.y, x1.z, x1.w};
#pragma unroll
            for (int i = 0; i < 4; ++i) {
                u32 pack = (u32)f2bf(v0[i]) | ((u32)f2bf(v1[i]) << 16);
                *(u32*)&Bls[4 * nq + i][2 * pr] = pack;
            }
        }
        __syncthreads();

        bf16x8 a0 = *(const bf16x8*)&Als[wr * 32 + 0 + l15][kg8];
        bf16x8 a1 = *(const bf16x8*)&Als[wr * 32 + 16 + l15][kg8];
        bf16x8 b0 = *(const bf16x8*)&Bls[wc * 32 + 0 + l15][kg8];
        bf16x8 b1 = *(const bf16x8*)&Bls[wc * 32 + 16 + l15][kg8];
        acc00 = __builtin_amdgcn_mfma_f32_16x16x32_bf16(a0, b0, acc00, 0, 0, 0);
        acc01 = __builtin_amdgcn_mfma_f32_16x16x32_bf16(a0, b1, acc01, 0, 0, 0);
        acc10 = __builtin_amdgcn_mfma_f32_16x16x32_bf16(a1, b0, acc10, 0, 0, 0);
        acc11 = __builtin_amdgcn_mfma_f32_16x16x32_bf16(a1, b1, acc11, 0, 0, 0);
        __syncthreads();
    }

    // epilogue: C/D layout (m89): col = lane&15, row = (lane>>4)*4 + j
    int rbase = m0 + wr * 32 + (lane >> 4) * 4;
    int cbase = n0 + wc * 32 + l15;
#pragma unroll
    for (int mf = 0; mf < 2; ++mf) {
#pragma unroll
        for (int nf = 0; nf < 2; ++nf) {
            f32x4 acc = mf == 0 ? (nf == 0 ? acc00 : acc01) : (nf == 0 ? acc10 : acc11);
            int col = cbase + nf * 16;
            float bv = bias[col];
#pragma unroll
            for (int j = 0; j < 4; ++j) {
                int row = rbase + mf * 16 + j;
                float v = acc[j] + bv;
                if (GELU) v = 0.5f * v * (1.0f + erff(v * 0.70710678118654752f));
                C[(size_t)row * N + col] = v;
            }
        }
    }
}

// ---------------- attention: per (b,head) block, thread = query row ----------------
__global__ __launch_bounds__(256) void attention_kernel(
    const float* __restrict__ q, const float* __restrict__ k, const float* __restrict__ v,
    const int* __restrict__ mask, float* __restrict__ ctx) {
    int bh = blockIdx.x;
    int b = bh / NH_, h = bh % NH_;
    int t = threadIdx.x;
    const float scale = 0.125f;
    float4 qv[16];
    const float4* qp = (const float4*)(q + ((size_t)(b * TT + t) * HH + h * DH_));
#pragma unroll
    for (int d = 0; d < 16; ++d) qv[d] = qp[d];
    const float* kbase = k + ((size_t)b * TT * HH + h * DH_);
    const float* vbase = v + ((size_t)b * TT * HH + h * DH_);
    __shared__ float bias_s[TT];
    bias_s[t] = (1.0f - (float)mask[b * TT + t]) * -10000.0f;
    __syncthreads();
    float mx = -1e30f;
    for (int kk = 0; kk < TT; ++kk) {
        const float4* kp = (const float4*)(kbase + (size_t)kk * HH);
        float s = 0.f;
#pragma unroll
        for (int d = 0; d < 16; ++d) {
            float4 k4 = kp[d];
            s += qv[d].x * k4.x + qv[d].y * k4.y + qv[d].z * k4.z + qv[d].w * k4.w;
        }
        s = s * scale + bias_s[kk];
        mx = fmaxf(mx, s);
    }
    float acc[64] = {};
    float l = 0.f;
    for (int kk = 0; kk < TT; ++kk) {
        const float4* kp = (const float4*)(kbase + (size_t)kk * HH);
        float s = 0.f;
#pragma unroll
        for (int d = 0; d < 16; ++d) {
            float4 k4 = kp[d];
            s += qv[d].x * k4.x + qv[d].y * k4.y + qv[d].z * k4.z + qv[d].w * k4.w;
        }
        s = s * scale + bias_s[kk];
        float p = expf(s - mx);
        l += p;
        const float4* vp = (const float4*)(vbase + (size_t)kk * HH);
#pragma unroll
        for (int d = 0; d < 16; ++d) {
            float4 v4 = vp[d];
            acc[4 * d + 0] += p * v4.x;
            acc[4 * d + 1] += p * v4.y;
            acc[4 * d + 2] += p * v4.z;
            acc[4 * d + 3] += p * v4.w;
        }
    }
    float inv = 1.0f / l;
    float4* cp = (float4*)(ctx + ((size_t)(b * TT + t) * HH + h * DH_));
#pragma unroll
    for (int d = 0; d < 16; ++d) {
        float4 o;
        o.x = acc[4 * d + 0] * inv;
        o.y = acc[4 * d + 1] * inv;
        o.z = acc[4 * d + 2] * inv;
        o.w = acc[4 * d + 3] * inv;
        cp[d] = o;
    }
}

// ---------------- transpose + fp32->bf16: dst[C][R] = bf16(src[R][C]) ----------------
__global__ void transpose_bf16_kernel(const float* __restrict__ src, u16* __restrict__ dst,
                                      int R, int C) {
    __shared__ float tile[32][33];
    int bx = blockIdx.x;   // along C
    int by = blockIdx.y;   // along R
    int tx = threadIdx.x, ty = threadIdx.y;   // block (32,8)
    int x = bx * 32 + tx;
#pragma unroll
    for (int i = 0; i < 32; i += 8) {
        tile[ty + i][tx] = src[(size_t)(by * 32 + ty + i) * C + x];
    }
    __syncthreads();
    int r = by * 32 + tx;
#pragma unroll
    for (int i = 0; i < 32; i += 8) {
        dst[(size_t)(bx * 32 + ty + i) * R + r] = f2bf(tile[tx][ty + i]);
    }
}

// ---------------- LSTM scan v2: block = (dir, batch), 256 threads ----------------
// WT is k-major bf16: WT[k][g], k in [0,256), g in [0,1024). Thread t owns gates
// 4t..4t+3 (coalesced 8B loads per k) and the h/c update for index t.
__global__ __launch_bounds__(256) void lstm2_kernel(
    const float* __restrict__ xg_f, const float* __restrict__ xg_b,
    const u16* __restrict__ WT_f, const u16* __restrict__ WT_b,
    const float* __restrict__ bhh_f, const float* __restrict__ bhh_b,
    float* __restrict__ hf, float* __restrict__ hb) {
    int dir = blockIdx.x >> 3;
    int b = blockIdx.x & 7;
    const float* xg = dir ? xg_b : xg_f;
    const u16* WT = dir ? WT_b : WT_f;
    const float* bhh = dir ? bhh_b : bhh_f;
    float* hout = dir ? hb : hf;
    int tid = threadIdx.x;
    __shared__ float h_s[LH_];
    __shared__ float g_s[4 * LH_];
    float bb0 = bhh[4 * tid + 0], bb1 = bhh[4 * tid + 1];
    float bb2 = bhh[4 * tid + 2], bb3 = bhh[4 * tid + 3];
    float c_r = 0.f;
    h_s[tid] = 0.f;
    __syncthreads();
    for (int step = 0; step < TT; ++step) {
        int t = dir ? (TT - 1 - step) : step;
        const float4 xg4 = *(const float4*)&xg[((size_t)b * TT + t) * (4 * LH_) + 4 * tid];
        float a0 = xg4.x + bb0, a1 = xg4.y + bb1, a2 = xg4.z + bb2, a3 = xg4.w + bb3;
        const u16* wp = WT + 4 * tid;
#pragma unroll 2
        for (int k4 = 0; k4 < LH_ / 4; ++k4) {
            float4 h4 = *(const float4*)&h_s[4 * k4];
            uint2 w0 = *(const uint2*)(wp + (size_t)(4 * k4 + 0) * 1024);
            uint2 w1 = *(const uint2*)(wp + (size_t)(4 * k4 + 1) * 1024);
            uint2 w2 = *(const uint2*)(wp + (size_t)(4 * k4 + 2) * 1024);
            uint2 w3 = *(const uint2*)(wp + (size_t)(4 * k4 + 3) * 1024);
            a0 += __uint_as_float(w0.x << 16) * h4.x;
            a1 += __uint_as_float(w0.x & 0xffff0000u) * h4.x;
            a2 += __uint_as_float(w0.y << 16) * h4.x;
            a3 += __uint_as_float(w0.y & 0xffff0000u) * h4.x;
            a0 += __uint_as_float(w1.x << 16) * h4.y;
            a1 += __uint_as_float(w1.x & 0xffff0000u) * h4.y;
            a2 += __uint_as_float(w1.y << 16) * h4.y;
            a3 += __uint_as_float(w1.y & 0xffff0000u) * h4.y;
            a0 += __uint_as_float(w2.x << 16) * h4.z;
            a1 += __uint_as_float(w2.x & 0xffff0000u) * h4.z;
            a2 += __uint_as_float(w2.y << 16) * h4.z;
            a3 += __uint_as_float(w2.y & 0xffff0000u) * h4.z;
            a0 += __uint_as_float(w3.x << 16) * h4.w;
            a1 += __uint_as_float(w3.x & 0xffff0000u) * h4.w;
            a2 += __uint_as_float(w3.y << 16) * h4.w;
            a3 += __uint_as_float(w3.y & 0xffff0000u) * h4.w;
        }
        g_s[4 * tid + 0] = a0; g_s[4 * tid + 1] = a1;
        g_s[4 * tid + 2] = a2; g_s[4 * tid + 3] = a3;
        __syncthreads();
        float ig = sigmf(g_s[tid]);
        float fg = sigmf(g_s[LH_ + tid]);
        float gg = tanhf(g_s[2 * LH_ + tid]);
        float og = sigmf(g_s[3 * LH_ + tid]);
        c_r = fg * c_r + ig * gg;
        float hh = og * tanhf(c_r);
        h_s[tid] = hh;
        hout[((size_t)b * TT + t) * LH_ + tid] = hh;
        __syncthreads();
    }
}

// ---------------- classifier: em = [hf;hb] @ W_clf + b ----------------
__global__ __launch_bounds__(256) void clf_kernel(
    const float* __restrict__ hf, const float* __restrict__ hb,
    const float* __restrict__ W, const float* __restrict__ bias, float* __restrict__ em) {
    int idx = blockIdx.x * blockDim.x + threadIdx.x;
    if (idx >= BB * TT * KK_) return;
    int row = idx / KK_, j = idx % KK_;
    float acc = bias[j];
    const float* hfp = hf + (size_t)row * LH_;
    const float* hbp = hb + (size_t)row * LH_;
    for (int kk = 0; kk < LH_; ++kk) acc += hfp[kk] * W[kk * KK_ + j];
    for (int kk = 0; kk < LH_; ++kk) acc += hbp[kk] * W[(LH_ + kk) * KK_ + j];
    em[idx] = acc;
}

// ---------------- CRF: single block ----------------
__global__ __launch_bounds__(128) void crf_kernel(
    const float* __restrict__ em, const int* __restrict__ labels, const int* __restrict__ mask,
    const float* __restrict__ cstart, const float* __restrict__ cend,
    const float* __restrict__ ctrans, float* __restrict__ out) {
    __shared__ float alpha[BB][KK_], nxt[BB][KK_], trans[KK_ * KK_];
    __shared__ float score_s[BB], logZ_s[BB];
    int tid = threadIdx.x;
    if (tid < KK_ * KK_) trans[tid] = ctrans[tid];
    __syncthreads();
    int b = tid / KK_, j = tid % KK_;
    if (tid < BB * KK_) alpha[b][j] = cstart[j] + em[(size_t)b * TT * KK_ + j];
    __syncthreads();
    for (int t = 1; t < TT; ++t) {
        if (tid < BB * KK_) {
            float m = -1e30f;
            for (int i = 0; i < KK_; ++i) m = fmaxf(m, alpha[b][i] + trans[i * KK_ + j]);
            float s = 0.f;
            for (int i = 0; i < KK_; ++i) s += expf(alpha[b][i] + trans[i * KK_ + j] - m);
            float nv = m + logf(s) + em[((size_t)b * TT + t) * KK_ + j];
            nxt[b][j] = (mask[b * TT + t] > 0) ? nv : alpha[b][j];
        }
        __syncthreads();
        if (tid < BB * KK_) alpha[b][j] = nxt[b][j];
        __syncthreads();
    }
    if (tid < BB) {
        int bb = tid;
        int l0 = labels[bb * TT];
        float sc = cstart[l0] + em[(size_t)bb * TT * KK_ + l0];
        int prev = l0;
        for (int t = 1; t < TT; ++t) {
            int lt = labels[bb * TT + t];
            float mf = (float)mask[bb * TT + t];
            sc += (trans[prev * KK_ + lt] + em[((size_t)bb * TT + t) * KK_ + lt]) * mf;
            prev = lt;
        }
        int ends = 0;
        for (int t = 0; t < TT; ++t) ends += mask[bb * TT + t];
        ends -= 1;
        int last = labels[bb * TT + ends];
        sc += cend[last];
        score_s[bb] = sc;
        float m = -1e30f;
        for (int jj = 0; jj < KK_; ++jj) m = fmaxf(m, alpha[bb][jj] + cend[jj]);
        float s = 0.f;
        for (int jj = 0; jj < KK_; ++jj) s += expf(alpha[bb][jj] + cend[jj] - m);
        logZ_s[bb] = m + logf(s);
    }
    __syncthreads();
    if (tid == 0) {
        float acc = 0.f;
        for (int bb = 0; bb < BB; ++bb) acc += score_s[bb] - logZ_s[bb];
        out[0] = -acc / (float)BB;
    }
}

extern "C" void kernel_launch(void* const* d_in, const int* in_sizes, int n_in,
                              void* d_out, int out_size, void* d_ws, size_t ws_size,
                              hipStream_t stream) {
    const int* input_ids = (const int*)d_in[0];
    const int* attn_mask = (const int*)d_in[1];
    const int* labels    = (const int*)d_in[2];
    const float* word_emb = (const float*)d_in[3];
    const float* pos_emb  = (const float*)d_in[4];
    const float* type_emb = (const float*)d_in[5];
    const float* emb_ln_g = (const float*)d_in[6];
    const float* emb_ln_b = (const float*)d_in[7];
    const float* Wq = (const float*)d_in[8];
    const float* bq = (const float*)d_in[9];
    const float* Wk = (const float*)d_in[10];
    const float* bk = (const float*)d_in[11];
    const float* Wv = (const float*)d_in[12];
    const float* bv = (const float*)d_in[13];
    const float* Wo = (const float*)d_in[14];
    const float* bo = (const float*)d_in[15];
    const float* ln1_g = (const float*)d_in[16];
    const float* ln1_b = (const float*)d_in[17];
    const float* Wf1 = (const float*)d_in[18];
    const float* bf1 = (const float*)d_in[19];
    const float* Wf2 = (const float*)d_in[20];
    const float* bf2 = (const float*)d_in[21];
    const float* ln2_g = (const float*)d_in[22];
    const float* ln2_b = (const float*)d_in[23];
    const float* w_ih_f = (const float*)d_in[24];
    const float* w_hh_f = (const float*)d_in[25];
    const float* b_ih_f = (const float*)d_in[26];
    const float* b_hh_f = (const float*)d_in[27];
    const float* w_ih_b = (const float*)d_in[28];
    const float* w_hh_b = (const float*)d_in[29];
    const float* b_ih_b = (const float*)d_in[30];
    const float* b_hh_b = (const float*)d_in[31];
    const float* W_clf  = (const float*)d_in[32];
    const float* b_clf  = (const float*)d_in[33];
    const float* crf_start = (const float*)d_in[34];
    const float* crf_end   = (const float*)d_in[35];
    const float* crf_trans = (const float*)d_in[36];

    const size_t NTOK = (size_t)BB * TT;          // 2048
    const size_t SZ = NTOK * HH;                  // 1,572,864 floats
    float* ws = (float*)d_ws;
    float* x    = ws;
    float* qb   = x + SZ;
    float* kb   = qb + SZ;
    float* vb   = kb + SZ;
    float* ctx  = vb + SZ;
    float* ab   = ctx + SZ;
    float* tmp  = ab + SZ;
    float* big  = tmp + SZ;                       // 2048*3072 floats (also holds xg)
    u16* wt_f   = (u16*)(big + (size_t)2048 * 3072);   // 262144 u16
    u16* wt_b   = wt_f + (size_t)256 * 1024;           // 262144 u16

    embed_ln_kernel<<<NTOK, 256, 0, stream>>>(input_ids, word_emb, pos_emb, type_emb,
                                              emb_ln_g, emb_ln_b, x);

    // LSTM recurrent-weight transpose+convert: WT[k][g] = bf16(w_hh[g][k])
    {
        dim3 blk(32, 8);
        dim3 grd(LH_ / 32, (4 * LH_) / 32);   // (8, 32)
        transpose_bf16_kernel<<<grd, blk, 0, stream>>>(w_hh_f, wt_f, 4 * LH_, LH_);
        transpose_bf16_kernel<<<grd, blk, 0, stream>>>(w_hh_b, wt_b, 4 * LH_, LH_);
    }

    dim3 gH(HH / 64, NTOK / 64);      // 12 x 32
    dim3 gF(FF_ / 64, NTOK / 64);     // 48 x 32
    dim3 gG((4 * LH_) / 64, NTOK / 64); // 16 x 32

    for (int l = 0; l < NL; ++l) {
        const float* wq = Wq + (size_t)l * HH * HH;
        const float* wk = Wk + (size_t)l * HH * HH;
        const float* wv = Wv + (size_t)l * HH * HH;
        const float* wo = Wo + (size_t)l * HH * HH;
        const float* bq_l = bq + (size_t)l * HH;
        const float* bk_l = bk + (size_t)l * HH;
        const float* bv_l = bv + (size_t)l * HH;
        const float* bo_l = bo + (size_t)l * HH;
        const float* g1 = ln1_g + (size_t)l * HH;
        const float* b1 = ln1_b + (size_t)l * HH;
        const float* wf1 = Wf1 + (size_t)l * HH * FF_;
        const float* bf1_l = bf1 + (size_t)l * FF_;
        const float* wf2 = Wf2 + (size_t)l * FF_ * HH;
        const float* bf2_l = bf2 + (size_t)l * HH;
        const float* g2 = ln2_g + (size_t)l * HH;
        const float* b2 = ln2_b + (size_t)l * HH;

        gemm_mfma_kernel<false, false><<<gH, 256, 0, stream>>>(x, wq, bq_l, qb, NTOK, HH, HH);
        gemm_mfma_kernel<false, false><<<gH, 256, 0, stream>>>(x, wk, bk_l, kb, NTOK, HH, HH);
        gemm_mfma_kernel<false, false><<<gH, 256, 0, stream>>>(x, wv, bv_l, vb, NTOK, HH, HH);
        attention_kernel<<<BB * NH_, 256, 0, stream>>>(qb, kb, vb, attn_mask, ctx);
        gemm_mfma_kernel<false, false><<<gH, 256, 0, stream>>>(ctx, wo, bo_l, tmp, NTOK, HH, HH);
        ln_residual_kernel<<<NTOK, 256, 0, stream>>>(x, tmp, g1, b1, ab);
        gemm_mfma_kernel<false, true><<<gF, 256, 0, stream>>>(ab, wf1, bf1_l, big, NTOK, FF_, HH);
        gemm_mfma_kernel<false, false><<<gH, 256, 0, stream>>>(big, wf2, bf2_l, tmp, NTOK, HH, FF_);
        ln_residual_kernel<<<NTOK, 256, 0, stream>>>(ab, tmp, g2, b2, x);
    }

    // LSTM input projections: xg[b,t,g] = x[b,t,:] . w_ih[g,:] + b_ih[g]  (B is [N][K])
    float* xg_f = big;
    float* xg_b = big + NTOK * (size_t)(4 * LH_);
    gemm_mfma_kernel<true, false><<<gG, 256, 0, stream>>>(x, w_ih_f, b_ih_f, xg_f, NTOK, 4 * LH_, HH);
    gemm_mfma_kernel<true, false><<<gG, 256, 0, stream>>>(x, w_ih_b, b_ih_b, xg_b, NTOK, 4 * LH_, HH);

    float* hf = qb;
    float* hb = kb;
    float* em = vb;
    lstm2_kernel<<<16, 256, 0, stream>>>(xg_f, xg_b, wt_f, wt_b, b_hh_f, b_hh_b, hf, hb);
    clf_kernel<<<(BB * TT * KK_ + 255) / 256, 256, 0, stream>>>(hf, hb, W_clf, b_clf, em);
    crf_kernel<<<1, 128, 0, stream>>>(em, labels, attn_mask, crf_start, crf_end, crf_trans,
                                      (float*)d_out);
}